// Round 1
// baseline (421.963 us; speedup 1.0000x reference)
//
#include <hip/hip_runtime.h>
#include <math.h>

// Deformable DETR multi-scale deformable attention — MI355X (gfx950)
// B=2, Lq=Lv=13294, D=256, H=8, HD=32, L=4, P=4
// Levels: (100,100),(50,50),(25,25),(13,13)  starts {0,10000,12500,13125}

namespace {
constexpr int LQ    = 13294;
constexpr int LV    = 13294;
constexpr int NL    = 4;
constexpr int NROWS = 2 * LQ;   // B * Lq = 26588
}

__device__ __constant__ int c_lw[4]    = {100, 50, 25, 13};     // square levels (h==w)
__device__ __constant__ int c_start[4] = {0, 10000, 12500, 13125};

// ---------------------------------------------------------------------------
// Generic 256->256 row GEMV, 8 rows per block. Y[row][j] = X[row]·W[:,j] + b[j]
// Safe for in-place X==Y: each block stages its own 8 rows in LDS first and
// no block reads another block's rows.
// ---------------------------------------------------------------------------
__global__ __launch_bounds__(256) void gemv8_256(
    const float* __restrict__ X, const float* __restrict__ W,
    const float* __restrict__ bias, float* __restrict__ Y, int nrows)
{
    __shared__ float xs[8][256];
    const int tid = threadIdx.x;
    const int r0  = blockIdx.x * 8;

    for (int i = tid; i < 8 * 256; i += 256) {
        const int r = i >> 8, k = i & 255;
        const int row = r0 + r;
        xs[r][k] = (row < nrows) ? X[(size_t)row * 256 + k] : 0.0f;
    }
    __syncthreads();

    float acc[8] = {0.f, 0.f, 0.f, 0.f, 0.f, 0.f, 0.f, 0.f};
    #pragma unroll 4
    for (int k = 0; k < 256; ++k) {
        const float w = W[(size_t)k * 256 + tid];
        #pragma unroll
        for (int r = 0; r < 8; ++r) acc[r] = fmaf(xs[r][k], w, acc[r]);
    }
    const float bb = bias[tid];
    #pragma unroll
    for (int r = 0; r < 8; ++r) {
        const int row = r0 + r;
        if (row < nrows) Y[(size_t)row * 256 + tid] = acc[r] + bb;
    }
}

// ---------------------------------------------------------------------------
// Fused: off = q@W_off+b_off ; logits = q@W_attn+b_attn ; softmax over 16 per
// head ; sampling coords x = (ref + off/w)*w - 0.5 stored as [row][128][2].
// 8 query rows per block.
// ---------------------------------------------------------------------------
__global__ __launch_bounds__(256) void off_attn_loc(
    const float* __restrict__ query, const float* __restrict__ refpts,
    const float* __restrict__ Woff,  const float* __restrict__ boff,
    const float* __restrict__ Wattn, const float* __restrict__ battn,
    float* __restrict__ sloc, float* __restrict__ awout)
{
    __shared__ float qs[8][256];
    __shared__ float offs[8][256];
    const int tid = threadIdx.x;
    const int r0  = blockIdx.x * 8;

    for (int i = tid; i < 8 * 256; i += 256) {
        const int r = i >> 8, k = i & 255;
        const int row = r0 + r;
        qs[r][k] = (row < NROWS) ? query[(size_t)row * 256 + k] : 0.0f;
    }
    __syncthreads();

    // --- offsets GEMV: 256 columns, all threads ---
    {
        float acc[8] = {0.f, 0.f, 0.f, 0.f, 0.f, 0.f, 0.f, 0.f};
        #pragma unroll 4
        for (int k = 0; k < 256; ++k) {
            const float w = Woff[(size_t)k * 256 + tid];
            #pragma unroll
            for (int r = 0; r < 8; ++r) acc[r] = fmaf(qs[r][k], w, acc[r]);
        }
        const float bb = boff[tid];
        #pragma unroll
        for (int r = 0; r < 8; ++r) offs[r][tid] = acc[r] + bb;
    }

    // --- attention GEMV: 128 columns (threads 0..127) ---
    float accA[8] = {0.f, 0.f, 0.f, 0.f, 0.f, 0.f, 0.f, 0.f};
    if (tid < 128) {
        #pragma unroll 4
        for (int k = 0; k < 256; ++k) {
            const float w = Wattn[(size_t)k * 128 + tid];
            #pragma unroll
            for (int r = 0; r < 8; ++r) accA[r] = fmaf(qs[r][k], w, accA[r]);
        }
    }
    __syncthreads();   // offs[][] visible

    if (tid < 128) {
        const float ba = battn[tid];
        const int   l  = (tid >> 2) & 3;         // tid = h*16 + l*4 + p
        const float wl = (float)c_lw[l];
        #pragma unroll
        for (int r = 0; r < 8; ++r) {
            const int row = r0 + r;
            if (row >= NROWS) break;             // uniform across the group
            // softmax over the 16 lanes sharing this head
            const float v = accA[r] + ba;
            float m = v;
            #pragma unroll
            for (int o = 8; o > 0; o >>= 1) m = fmaxf(m, __shfl_xor(m, o, 16));
            const float e = expf(v - m);
            float ssum = e;
            #pragma unroll
            for (int o = 8; o > 0; o >>= 1) ssum += __shfl_xor(ssum, o, 16);
            awout[(size_t)row * 128 + tid] = e / ssum;
            // sampling location (levels are square: h==w)
            const float ox = offs[r][2 * tid];
            const float oy = offs[r][2 * tid + 1];
            const float rx = refpts[((size_t)row * NL + l) * 2 + 0];
            const float ry = refpts[((size_t)row * NL + l) * 2 + 1];
            const float lx = rx + ox / wl;
            const float ly = ry + oy / wl;
            sloc[(size_t)row * 256 + 2 * tid]     = lx * wl - 0.5f;
            sloc[(size_t)row * 256 + 2 * tid + 1] = ly * wl - 0.5f;
        }
    }
}

// ---------------------------------------------------------------------------
// Bilinear sampling + attention-weighted sum. One block per (b,q) row;
// thread = h*32 + c. Output layout [row][h*32+c] (pre output-projection).
// ---------------------------------------------------------------------------
__global__ __launch_bounds__(256) void ms_sample(
    const float* __restrict__ vproj, const float* __restrict__ sloc,
    const float* __restrict__ aw, float* __restrict__ out)
{
    __shared__ float sx[128], sy[128], sw[128];
    const int row = blockIdx.x;
    const int b   = row / LQ;
    const int tid = threadIdx.x;
    if (tid < 128) {
        sx[tid] = sloc[(size_t)row * 256 + 2 * tid];
        sy[tid] = sloc[(size_t)row * 256 + 2 * tid + 1];
        sw[tid] = aw[(size_t)row * 128 + tid];
    }
    __syncthreads();

    const int h = tid >> 5, c = tid & 31;
    const float* __restrict__ vb = vproj + (size_t)b * LV * 256 + h * 32 + c;

    constexpr int lw_[4] = {100, 50, 25, 13};
    constexpr int st_[4] = {0, 10000, 12500, 13125};

    float acc = 0.f;
    #pragma unroll
    for (int s = 0; s < 16; ++s) {
        const int l  = s >> 2;          // compile-time after unroll
        const int wl = lw_[l];
        const int st = st_[l];
        const int j  = h * 16 + s;
        const float x = sx[j], y = sy[j], a = sw[j];
        const float x0f = floorf(x), y0f = floorf(y);
        const int   x0  = (int)x0f,  y0  = (int)y0f;
        const float wx1 = x - x0f, wx0 = 1.f - wx1;
        const float wy1 = y - y0f, wy0 = 1.f - wy1;
        const bool xv0 = (x0     >= 0) && (x0     < wl);
        const bool xv1 = (x0 + 1 >= 0) && (x0 + 1 < wl);
        const bool yv0 = (y0     >= 0) && (y0     < wl);
        const bool yv1 = (y0 + 1 >= 0) && (y0 + 1 < wl);
        float v00 = 0.f, v10 = 0.f, v01 = 0.f, v11 = 0.f;
        if (xv0 && yv0) v00 = vb[(size_t)(st +  y0      * wl + x0    ) * 256];
        if (xv1 && yv0) v10 = vb[(size_t)(st +  y0      * wl + x0 + 1) * 256];
        if (xv0 && yv1) v01 = vb[(size_t)(st + (y0 + 1) * wl + x0    ) * 256];
        if (xv1 && yv1) v11 = vb[(size_t)(st + (y0 + 1) * wl + x0 + 1) * 256];
        acc += a * (wy0 * (wx0 * v00 + wx1 * v10) + wy1 * (wx0 * v01 + wx1 * v11));
    }
    out[(size_t)row * 256 + tid] = acc;
}

extern "C" void kernel_launch(void* const* d_in, const int* in_sizes, int n_in,
                              void* d_out, int out_size, void* d_ws, size_t ws_size,
                              hipStream_t stream)
{
    const float* query  = (const float*)d_in[0];
    const float* refpts = (const float*)d_in[1];
    const float* value  = (const float*)d_in[2];
    // d_in[3] = spatial_shapes (static, baked in)
    const float* Woff   = (const float*)d_in[4];
    const float* boff   = (const float*)d_in[5];
    const float* Wattn  = (const float*)d_in[6];
    const float* battn  = (const float*)d_in[7];
    const float* Wv     = (const float*)d_in[8];
    const float* bv     = (const float*)d_in[9];
    const float* Wout   = (const float*)d_in[10];
    const float* bout   = (const float*)d_in[11];
    float* out = (float*)d_out;

    float* ws    = (float*)d_ws;
    float* vproj = ws;                               // NROWS*256 floats
    float* sloc  = vproj + (size_t)NROWS * 256;      // NROWS*256 floats
    float* aw    = sloc  + (size_t)NROWS * 256;      // NROWS*128 floats

    const int nblk = (NROWS + 7) / 8;                // 3324

    hipLaunchKernelGGL(gemv8_256, dim3(nblk), dim3(256), 0, stream,
                       value, Wv, bv, vproj, NROWS);
    hipLaunchKernelGGL(off_attn_loc, dim3(nblk), dim3(256), 0, stream,
                       query, refpts, Woff, boff, Wattn, battn, sloc, aw);
    hipLaunchKernelGGL(ms_sample, dim3(NROWS), dim3(256), 0, stream,
                       vproj, sloc, aw, out);
    hipLaunchKernelGGL(gemv8_256, dim3(nblk), dim3(256), 0, stream,
                       out, Wout, bout, out, NROWS);
}